// Round 1
// baseline (751.329 us; speedup 1.0000x reference)
//
#include <hip/hip_runtime.h>
#include <hip/hip_bf16.h>

// Problem constants (fixed by setup_inputs)
constexpr int B  = 16;
constexpr int N  = 4096;
constexpr int NP = 1024;
constexpr int C  = 64;
constexpr int NS = 32;            // nsample
constexpr int OC = C + 3;         // output channels = 67
constexpr float R2 = 0.2f * 0.2f; // radius^2

constexpr int TILE = 1024;        // xyz points staged in LDS per tile

// Kernel 1: ball query + write grouped_xyz channels (0..2) + idx to workspace.
// One thread per center. All threads of a block share the same batch b
// (256 | NP), so LDS staging of xyz[b] tiles is shared.
__global__ __launch_bounds__(256)
void ball_query_kernel(const float* __restrict__ xyz,
                       const float* __restrict__ new_xyz,
                       float* __restrict__ out,
                       int* __restrict__ ws_idx)
{
    __shared__ float s_xyz[TILE * 3];

    const int g = blockIdx.x * 256 + threadIdx.x; // center id in [0, B*NP)
    const int b = g >> 10;                        // g / NP
    const int p = g & (NP - 1);                   // g % NP

    const float qx = new_xyz[g * 3 + 0];
    const float qy = new_xyz[g * 3 + 1];
    const float qz = new_xyz[g * 3 + 2];

    const float* xb = xyz + (size_t)b * N * 3;

    int   cnt = 0;
    int   fidx = 0;
    float fdx = 0.f, fdy = 0.f, fdz = 0.f;

    float* out_x = out + (((size_t)b * OC + 0) * NP + p) * NS;
    float* out_y = out + (((size_t)b * OC + 1) * NP + p) * NS;
    float* out_z = out + (((size_t)b * OC + 2) * NP + p) * NS;
    int*   idx_p = ws_idx + (size_t)g * NS;

    for (int t0 = 0; t0 < N; t0 += TILE) {
        // cooperative load of TILE points (TILE*3 floats, contiguous)
        #pragma unroll
        for (int i = threadIdx.x; i < TILE * 3; i += 256)
            s_xyz[i] = xb[t0 * 3 + i];
        __syncthreads();

        if (cnt < NS) {
            for (int j = 0; j < TILE; ++j) {
                if (cnt >= NS) break;
                const float x = s_xyz[j * 3 + 0];
                const float y = s_xyz[j * 3 + 1];
                const float z = s_xyz[j * 3 + 2];
                const float dx = x - qx;
                const float dy = y - qy;
                const float dz = z - qz;
                // match numpy float32: ((dx*dx)+(dy*dy))+(dz*dz), no FMA fusion
                const float d2 = __fadd_rn(__fadd_rn(__fmul_rn(dx, dx),
                                                     __fmul_rn(dy, dy)),
                                           __fmul_rn(dz, dz));
                if (d2 < R2) {
                    if (cnt == 0) { fdx = dx; fdy = dy; fdz = dz; fidx = t0 + j; }
                    idx_p[cnt] = t0 + j;
                    out_x[cnt] = dx;
                    out_y[cnt] = dy;
                    out_z[cnt] = dz;
                    ++cnt;
                }
            }
        }
        __syncthreads();
    }

    if (cnt == 0) {
        // no point in radius: reference fills idx with 0
        fidx = 0;
        fdx = xb[0] - qx;
        fdy = xb[1] - qy;
        fdz = xb[2] - qz;
    }
    for (int s = cnt; s < NS; ++s) {
        idx_p[s] = fidx;
        out_x[s] = fdx;
        out_y[s] = fdy;
        out_z[s] = fdz;
    }
}

// Kernel 2: grouped_points — out[b, 3+c, p, s] = points[b, c, idx[b,p,s]]
// One thread per output element; coalesced writes along s; gather reads hit
// a 16 KB points row that stays in L1/L2 across the block.
__global__ __launch_bounds__(256)
void group_points_kernel(const float* __restrict__ points,
                         const int* __restrict__ ws_idx,
                         float* __restrict__ out)
{
    const unsigned t = blockIdx.x * 256u + threadIdx.x; // over B*C*NP*NS
    const int s = t & 31;
    const int p = (t >> 5) & (NP - 1);
    const int c = (t >> 15) & (C - 1);
    const int b = t >> 21;

    const int idx = ws_idx[(((size_t)b * NP) + p) * NS + s];
    const float v = points[(((size_t)b * C) + c) * N + idx];
    out[((((size_t)b * OC) + 3 + c) * NP + p) * NS + s] = v;
}

extern "C" void kernel_launch(void* const* d_in, const int* in_sizes, int n_in,
                              void* d_out, int out_size, void* d_ws, size_t ws_size,
                              hipStream_t stream)
{
    const float* xyz     = (const float*)d_in[0]; // (B, N, 3)
    const float* new_xyz = (const float*)d_in[1]; // (B, NP, 3)
    const float* points  = (const float*)d_in[2]; // (B, C, N)
    float* out = (float*)d_out;                   // (B, 67, NP, NS)
    int* ws_idx = (int*)d_ws;                     // (B*NP*NS) ints = 2 MB

    ball_query_kernel<<<(B * NP) / 256, 256, 0, stream>>>(xyz, new_xyz, out, ws_idx);

    const int total = B * C * NP * NS; // 33,554,432
    group_points_kernel<<<total / 256, 256, 0, stream>>>(points, ws_idx, out);
}

// Round 3
// 208.865 us; speedup vs baseline: 3.5972x; 3.5972x over previous
//
#include <hip/hip_runtime.h>
#include <hip/hip_bf16.h>

// Problem constants (fixed by setup_inputs)
constexpr int B  = 16;
constexpr int N  = 4096;
constexpr int NP = 1024;
constexpr int C  = 64;
constexpr int NS = 32;            // nsample
constexpr int OC = C + 3;         // output channels = 67
constexpr float R2 = 0.2f * 0.2f; // radius^2

// native vector types (HIP_vector_type float4 is rejected by
// __builtin_nontemporal_store; clang ext_vector_type works)
typedef float v4f __attribute__((ext_vector_type(4)));
typedef int   v4i __attribute__((ext_vector_type(4)));

// Kernel 1: ball query, one WAVE per center. The wave scans 64 points per
// iteration in lockstep; ballot + prefix-popcount assigns slots in index
// order (matches reference "first nsample in index order" exactly).
// Also writes grouped_xyz channels (0..2) and idx to workspace.
__global__ __launch_bounds__(256)
void ball_query_kernel(const float* __restrict__ xyz,
                       const float* __restrict__ new_xyz,
                       float* __restrict__ out,
                       int* __restrict__ ws_idx)
{
    const int wid  = (blockIdx.x << 2) + (threadIdx.x >> 6); // center id (wave-uniform)
    const int lane = threadIdx.x & 63;
    const int b = wid >> 10;        // wid / NP
    const int p = wid & (NP - 1);   // wid % NP

    const float qx = new_xyz[wid * 3 + 0];  // wave-uniform -> s_load
    const float qy = new_xyz[wid * 3 + 1];
    const float qz = new_xyz[wid * 3 + 2];

    const float* xb = xyz + (size_t)b * N * 3;

    float* out_x = out + (((size_t)b * OC + 0) * NP + p) * NS;
    float* out_y = out + (((size_t)b * OC + 1) * NP + p) * NS;
    float* out_z = out + (((size_t)b * OC + 2) * NP + p) * NS;
    int*   idx_p = ws_idx + (size_t)wid * NS;

    // defaults: reference fills with index 0 when no point is in radius
    float fdx = xb[0] - qx;
    float fdy = xb[1] - qy;
    float fdz = xb[2] - qz;
    int   fidx = 0;

    int cnt = 0;
    for (int base = 0; base < N && cnt < NS; base += 64) {
        const int jj = base + lane;
        const float x = xb[jj * 3 + 0];
        const float y = xb[jj * 3 + 1];
        const float z = xb[jj * 3 + 2];
        const float dx = x - qx;
        const float dy = y - qy;
        const float dz = z - qz;
        // match numpy float32: ((dx*dx)+(dy*dy))+(dz*dz), block FMA fusion
        const float d2 = __fadd_rn(__fadd_rn(__fmul_rn(dx, dx),
                                             __fmul_rn(dy, dy)),
                                   __fmul_rn(dz, dz));
        const bool in = d2 < R2;
        const unsigned long long mask = __ballot(in);

        if (cnt == 0 && mask != 0ull) {
            const int fl = __ffsll((unsigned long long)mask) - 1;
            fdx = __shfl(dx, fl, 64);
            fdy = __shfl(dy, fl, 64);
            fdz = __shfl(dz, fl, 64);
            fidx = base + fl;
        }
        if (in) {
            const int slot = cnt + __popcll(mask & ((1ull << lane) - 1ull));
            if (slot < NS) {
                idx_p[slot] = jj;
                out_x[slot] = dx;
                out_y[slot] = dy;
                out_z[slot] = dz;
            }
        }
        cnt += (int)__popcll(mask);
    }

    const int cntc = cnt < NS ? cnt : NS;
    if (lane >= cntc && lane < NS) {
        idx_p[lane] = fidx;
        out_x[lane] = fdx;
        out_y[lane] = fdy;
        out_z[lane] = fdz;
    }
}

// Kernel 2: grouped_points. One block per (b,c): stage the 16 KB points row
// in LDS, then gather with int4 idx loads + float4 streaming stores.
__global__ __launch_bounds__(256)
void group_points_kernel(const float* __restrict__ points,
                         const int* __restrict__ ws_idx,
                         float* __restrict__ out)
{
    __shared__ float s_row[N]; // 16 KB

    const int bc = blockIdx.x;      // over B*C = 1024
    const int b = bc >> 6;
    const int c = bc & (C - 1);

    const v4f* row4 = (const v4f*)(points + ((size_t)b * C + c) * N);
    v4f* s4 = (v4f*)s_row;
    #pragma unroll
    for (int i = threadIdx.x; i < N / 4; i += 256)
        s4[i] = row4[i];
    __syncthreads();

    const v4i* idx4 = (const v4i*)(ws_idx + (size_t)b * NP * NS);
    v4f* out4 = (v4f*)(out + ((size_t)b * OC + 3 + c) * NP * NS);

    for (int t = threadIdx.x; t < NP * NS / 4; t += 256) {
        const v4i id = idx4[t];
        v4f v;
        v.x = s_row[id.x];
        v.y = s_row[id.y];
        v.z = s_row[id.z];
        v.w = s_row[id.w];
        __builtin_nontemporal_store(v, &out4[t]);
    }
}

extern "C" void kernel_launch(void* const* d_in, const int* in_sizes, int n_in,
                              void* d_out, int out_size, void* d_ws, size_t ws_size,
                              hipStream_t stream)
{
    const float* xyz     = (const float*)d_in[0]; // (B, N, 3)
    const float* new_xyz = (const float*)d_in[1]; // (B, NP, 3)
    const float* points  = (const float*)d_in[2]; // (B, C, N)
    float* out = (float*)d_out;                   // (B, 67, NP, NS)
    int* ws_idx = (int*)d_ws;                     // B*NP*NS ints = 2 MB

    // one wave per center, 4 waves per block
    ball_query_kernel<<<(B * NP) / 4, 256, 0, stream>>>(xyz, new_xyz, out, ws_idx);

    // one block per (b, c)
    group_points_kernel<<<B * C, 256, 0, stream>>>(points, ws_idx, out);
}

// Round 4
// 195.161 us; speedup vs baseline: 3.8498x; 1.0702x over previous
//
#include <hip/hip_runtime.h>
#include <hip/hip_bf16.h>

// Problem constants (fixed by setup_inputs)
constexpr int B  = 16;
constexpr int N  = 4096;
constexpr int NP = 1024;
constexpr int C  = 64;
constexpr int NS = 32;            // nsample
constexpr int OC = C + 3;         // output channels = 67
constexpr float R2 = 0.2f * 0.2f; // radius^2

// native vector types (HIP_vector_type float4 is rejected by
// __builtin_nontemporal_store; clang ext_vector_type works)
typedef float v4f __attribute__((ext_vector_type(4)));
typedef int   v4i __attribute__((ext_vector_type(4)));

// Kernel 1: ball query, one WAVE per center, 128 points (2 per lane) per
// iteration. Two ordered ballots + prefix-popcount assign slots in index
// order (exact reference semantics: first `nsample` in index order, unfilled
// slots replicate the first hit, idx 0 if none).
__global__ __launch_bounds__(256)
void ball_query_kernel(const float* __restrict__ xyz,
                       const float* __restrict__ new_xyz,
                       float* __restrict__ out,
                       int* __restrict__ ws_idx)
{
    const int wid  = (blockIdx.x << 2) + (threadIdx.x >> 6); // center id (wave-uniform)
    const int lane = threadIdx.x & 63;
    const int b = wid >> 10;        // wid / NP
    const int p = wid & (NP - 1);   // wid % NP

    const float qx = new_xyz[wid * 3 + 0];  // wave-uniform
    const float qy = new_xyz[wid * 3 + 1];
    const float qz = new_xyz[wid * 3 + 2];

    const float* xb = xyz + (size_t)b * N * 3;

    float* out_x = out + (((size_t)b * OC + 0) * NP + p) * NS;
    float* out_y = out + (((size_t)b * OC + 1) * NP + p) * NS;
    float* out_z = out + (((size_t)b * OC + 2) * NP + p) * NS;
    int*   idx_p = ws_idx + (size_t)wid * NS;

    // defaults: reference fills with index 0 when no point is in radius
    float fdx = xb[0] - qx;
    float fdy = xb[1] - qy;
    float fdz = xb[2] - qz;
    int   fidx = 0;

    int cnt = 0;
    for (int base = 0; base < N && cnt < NS; base += 128) {
        const int j0 = base + lane;
        const int j1 = base + 64 + lane;

        const float x0 = xb[j0 * 3 + 0];
        const float y0 = xb[j0 * 3 + 1];
        const float z0 = xb[j0 * 3 + 2];
        const float x1 = xb[j1 * 3 + 0];
        const float y1 = xb[j1 * 3 + 1];
        const float z1 = xb[j1 * 3 + 2];

        const float dx0 = x0 - qx, dy0 = y0 - qy, dz0 = z0 - qz;
        const float dx1 = x1 - qx, dy1 = y1 - qy, dz1 = z1 - qz;
        // match numpy float32: ((dx*dx)+(dy*dy))+(dz*dz), block FMA fusion
        const float d20 = __fadd_rn(__fadd_rn(__fmul_rn(dx0, dx0),
                                              __fmul_rn(dy0, dy0)),
                                    __fmul_rn(dz0, dz0));
        const float d21 = __fadd_rn(__fadd_rn(__fmul_rn(dx1, dx1),
                                              __fmul_rn(dy1, dy1)),
                                    __fmul_rn(dz1, dz1));
        const bool in0 = d20 < R2;
        const bool in1 = d21 < R2;
        const unsigned long long m0 = __ballot(in0);
        const unsigned long long m1 = __ballot(in1);

        if (cnt == 0) {
            if (m0 != 0ull) {
                const int fl = __ffsll(m0) - 1;
                fdx = __shfl(dx0, fl, 64);
                fdy = __shfl(dy0, fl, 64);
                fdz = __shfl(dz0, fl, 64);
                fidx = base + fl;
            } else if (m1 != 0ull) {
                const int fl = __ffsll(m1) - 1;
                fdx = __shfl(dx1, fl, 64);
                fdy = __shfl(dy1, fl, 64);
                fdz = __shfl(dz1, fl, 64);
                fidx = base + 64 + fl;
            }
        }

        const unsigned long long below = (1ull << lane) - 1ull;
        if (in0) {
            const int slot = cnt + (int)__popcll(m0 & below);
            if (slot < NS) {
                idx_p[slot] = j0;
                out_x[slot] = dx0;
                out_y[slot] = dy0;
                out_z[slot] = dz0;
            }
        }
        const int c0 = cnt + (int)__popcll(m0);
        if (in1) {
            const int slot = c0 + (int)__popcll(m1 & below);
            if (slot < NS) {
                idx_p[slot] = j1;
                out_x[slot] = dx1;
                out_y[slot] = dy1;
                out_z[slot] = dz1;
            }
        }
        cnt = c0 + (int)__popcll(m1);
    }

    const int cntc = cnt < NS ? cnt : NS;
    if (lane >= cntc && lane < NS) {
        idx_p[lane] = fidx;
        out_x[lane] = fdx;
        out_y[lane] = fdy;
        out_z[lane] = fdz;
    }
}

// Kernel 2: grouped_points. One block per (b, pair-of-channels): stage two
// contiguous 16 KB points rows in LDS (one 32 KB contiguous copy), then each
// int4 idx load feeds two float4 streaming stores. Halves idx traffic vs
// one-channel-per-block.
__global__ __launch_bounds__(256)
void group_points_kernel(const float* __restrict__ points,
                         const int* __restrict__ ws_idx,
                         float* __restrict__ out)
{
    __shared__ float s_row[2 * N]; // 32 KB

    const int bc = blockIdx.x;           // over B * (C/2) = 512
    const int b  = bc >> 5;
    const int c2 = (bc & 31) * 2;        // first of the two channels

    // rows c2 and c2+1 are contiguous in memory: one 8192-float copy
    const v4f* row4 = (const v4f*)(points + ((size_t)b * C + c2) * N);
    v4f* s4 = (v4f*)s_row;
    #pragma unroll
    for (int i = threadIdx.x; i < 2 * N / 4; i += 256)
        s4[i] = row4[i];
    __syncthreads();

    const v4i* idx4 = (const v4i*)(ws_idx + (size_t)b * NP * NS);
    v4f* out0 = (v4f*)(out + ((size_t)b * OC + 3 + c2) * NP * NS);
    v4f* out1 = (v4f*)(out + ((size_t)b * OC + 4 + c2) * NP * NS);

    for (int t = threadIdx.x; t < NP * NS / 4; t += 256) {
        const v4i id = idx4[t];
        v4f va, vb;
        va.x = s_row[id.x];
        va.y = s_row[id.y];
        va.z = s_row[id.z];
        va.w = s_row[id.w];
        vb.x = s_row[N + id.x];
        vb.y = s_row[N + id.y];
        vb.z = s_row[N + id.z];
        vb.w = s_row[N + id.w];
        __builtin_nontemporal_store(va, &out0[t]);
        __builtin_nontemporal_store(vb, &out1[t]);
    }
}

extern "C" void kernel_launch(void* const* d_in, const int* in_sizes, int n_in,
                              void* d_out, int out_size, void* d_ws, size_t ws_size,
                              hipStream_t stream)
{
    const float* xyz     = (const float*)d_in[0]; // (B, N, 3)
    const float* new_xyz = (const float*)d_in[1]; // (B, NP, 3)
    const float* points  = (const float*)d_in[2]; // (B, C, N)
    float* out = (float*)d_out;                   // (B, 67, NP, NS)
    int* ws_idx = (int*)d_ws;                     // B*NP*NS ints = 2 MB

    // one wave per center, 4 waves per block
    ball_query_kernel<<<(B * NP) / 4, 256, 0, stream>>>(xyz, new_xyz, out, ws_idx);

    // one block per (b, channel-pair)
    group_points_kernel<<<B * (C / 2), 256, 0, stream>>>(points, ws_idx, out);
}